// Round 13
// baseline (318.310 us; speedup 1.0000x reference)
//
#include <hip/hip_runtime.h>
#include <math.h>

#define BB 64
#define NN 1224
#define CC 1024
#define DD 256
#define PP 200
#define TT 1024
#define HH 4
#define HDD 64

typedef __attribute__((ext_vector_type(8))) short bf16x8;
typedef __attribute__((ext_vector_type(4))) float f32x4;
typedef unsigned short u16;
typedef unsigned long long u64;

__device__ __forceinline__ u16 f2bf(float f) {
  union { float f; unsigned int u; } v; v.f = f;
  unsigned int r = v.u + 0x7FFF + ((v.u >> 16) & 1);
  return (u16)(r >> 16);
}
__device__ __forceinline__ float bf2f(u16 h) {
  union { unsigned int u; float f; } v; v.u = ((unsigned int)h) << 16;
  return v.f;
}
__device__ __forceinline__ unsigned int pk2(float a, float b) {
  return (unsigned int)f2bf(a) | ((unsigned int)f2bf(b) << 16);
}
__device__ __forceinline__ void gload16(const void* g, void* l) {
  __builtin_amdgcn_global_load_lds(
      (const __attribute__((address_space(1))) void*)g,
      (__attribute__((address_space(3))) void*)l, 16, 0, 0);
}
__device__ __forceinline__ f32x4 ntld4(const float* p) {
  return __builtin_nontemporal_load((const f32x4*)p);
}

// ---------------- workspace layout (bytes) ----------------
static const size_t SZ_DOWN = (size_t)BB * NN * DD * 2;
static const size_t SZ_TOKT = (size_t)BB * DD * TT * 2;
static const size_t SZ_Q    = (size_t)BB * HH * PP * HDD * 2;
static const size_t SZ_SCORES = (size_t)BB * PP * TT * 2;

static const size_t B_DOWN   = 0;
static const size_t B_TOKT   = B_DOWN + SZ_DOWN;
static const size_t B_POOL   = B_TOKT + SZ_TOKT;
static const size_t B_QB     = B_POOL;
static const size_t B_KB     = B_QB + SZ_Q;
static const size_t B_VB     = B_KB + SZ_Q;
static const size_t B_SA     = B_VB + SZ_Q;
static const size_t B_SA2    = B_SA + SZ_Q;
static const size_t B_POUTBF = B_SA2;               // pout tile (sa2 never materialized)
static const size_t B_SCORES = B_SA2 + SZ_Q;
static const size_t B_W      = B_SCORES + SZ_SCORES * 2;
static const size_t B_WD     = B_W;
static const size_t B_WU     = B_WD + 524288;
static const size_t B_WIP    = B_WU + 524288;
static const size_t B_WOP    = B_WIP + 393216;

// ---------------- 64x256-tile pieces ----------------
#define MFMA_STEP64(Ab, Bb) \
  _Pragma("unroll") \
  for (int kk = 0; kk < 64; kk += 32) { \
    bf16x8 af[4], bfr[2]; \
    _Pragma("unroll") \
    for (int mi = 0; mi < 4; ++mi) { \
      const int R = mi * 16 + (lane & 15); \
      const int byt = (R * 128 + (kk + (lane >> 4) * 8) * 2) ^ ((R & 7) << 4); \
      af[mi] = *(const bf16x8*)((const char*)(Ab) + byt); \
    } \
    _Pragma("unroll") \
    for (int ni = 0; ni < 2; ++ni) { \
      const int R = wave * 32 + ni * 16 + (lane & 15); \
      const int byt = (R * 128 + (kk + (lane >> 4) * 8) * 2) ^ ((R & 7) << 4); \
      bfr[ni] = *(const bf16x8*)((const char*)(Bb) + byt); \
    } \
    _Pragma("unroll") \
    for (int mi = 0; mi < 4; ++mi) \
      _Pragma("unroll") \
      for (int ni = 0; ni < 2; ++ni) \
        acc[mi][ni] = __builtin_amdgcn_mfma_f32_16x16x32_bf16(af[mi], bfr[ni], acc[mi][ni], 0, 0, 0); \
  }

// A from persistent LDS Afull (64 x 256, pitch 512B, swizzled)
#define MFMA_AF(SACC, K0, Bbuf) \
  _Pragma("unroll") \
  for (int kk = 0; kk < 64; kk += 32) { \
    bf16x8 af[4], bfr[2]; \
    _Pragma("unroll") \
    for (int mi = 0; mi < 4; ++mi) { \
      const int R = mi * 16 + (lane & 15); \
      const int byt = (R * 512 + ((K0) + kk + (lane >> 4) * 8) * 2) ^ ((R & 7) << 4); \
      af[mi] = *(const bf16x8*)((const char*)Afull + byt); \
    } \
    _Pragma("unroll") \
    for (int ni = 0; ni < 2; ++ni) { \
      const int R = wave * 32 + ni * 16 + (lane & 15); \
      const int byt = (R * 128 + (kk + (lane >> 4) * 8) * 2) ^ ((R & 7) << 4); \
      bfr[ni] = *(const bf16x8*)((const char*)(Bbuf) + byt); \
    } \
    _Pragma("unroll") \
    for (int mi = 0; mi < 4; ++mi) \
      _Pragma("unroll") \
      for (int ni = 0; ni < 2; ++ni) \
        SACC[mi][ni] = __builtin_amdgcn_mfma_f32_16x16x32_bf16(af[mi], bfr[ni], SACC[mi][ni], 0, 0, 0); \
  }

// PV: A = P from Ph (64 x 512, pitch 1024B, swizzled), k = t_local
#define MFMA_PV(O, T0, Bbuf) \
  _Pragma("unroll") \
  for (int kk = 0; kk < 64; kk += 32) { \
    bf16x8 af[4], bfr[2]; \
    _Pragma("unroll") \
    for (int mi = 0; mi < 4; ++mi) { \
      const int R = mi * 16 + (lane & 15); \
      const int byt = (R * 1024 + ((T0) + kk + (lane >> 4) * 8) * 2) ^ ((R & 7) << 4); \
      af[mi] = *(const bf16x8*)((const char*)Ph + byt); \
    } \
    _Pragma("unroll") \
    for (int ni = 0; ni < 2; ++ni) { \
      const int R = wave * 32 + ni * 16 + (lane & 15); \
      const int byt = (R * 128 + (kk + (lane >> 4) * 8) * 2) ^ ((R & 7) << 4); \
      bfr[ni] = *(const bf16x8*)((const char*)(Bbuf) + byt); \
    } \
    _Pragma("unroll") \
    for (int mi = 0; mi < 4; ++mi) \
      _Pragma("unroll") \
      for (int ni = 0; ni < 2; ++ni) \
        O[mi][ni] = __builtin_amdgcn_mfma_f32_16x16x32_bf16(af[mi], bfr[ni], O[mi][ni], 0, 0, 0); \
  }

#define GLOAD_A1(Ab, SRC) \
  { \
    const int L = wave * 1024 + lane * 16; \
    const int r = L >> 7; \
    const int ce = ((L & 127) ^ ((r & 7) << 4)) >> 1; \
    gload16((SRC), (char*)(Ab) + wave * 1024); \
  }

#define GLOAD_B4(Bb, SRC) \
  _Pragma("unroll") \
  for (int ii = 0; ii < 4; ++ii) { \
    const int slot = wave * 4 + ii; \
    const int L = slot * 1024 + lane * 16; \
    const int r = L >> 7; \
    const int ce = ((L & 127) ^ ((r & 7) << 4)) >> 1; \
    gload16((SRC), (char*)(Bb) + slot * 1024); \
  }

#define PIPE_WAIT(N) asm volatile("s_waitcnt vmcnt(" #N ")" ::: "memory");
#define PIPE_BAR() \
  __builtin_amdgcn_s_barrier(); \
  __builtin_amdgcn_sched_barrier(0);
#define PIPE_END() \
  asm volatile("s_waitcnt lgkmcnt(0)" ::: "memory"); \
  __builtin_amdgcn_s_barrier(); \
  __builtin_amdgcn_sched_barrier(0);
#define LGKM_BAR() \
  asm volatile("s_waitcnt lgkmcnt(0)" ::: "memory"); \
  __builtin_amdgcn_s_barrier(); \
  __builtin_amdgcn_sched_barrier(0);

// ================= K0: cast all weights to bf16 =================
__global__ __launch_bounds__(256) void k_castw(const float* __restrict__ dW,
                                               const float* __restrict__ uW,
                                               const float* __restrict__ iW,
                                               const float* __restrict__ oW,
                                               u16* __restrict__ dWb, u16* __restrict__ uWb,
                                               u16* __restrict__ iWb, u16* __restrict__ oWb)
{
  const int id = blockIdx.x * 256 + threadIdx.x;
  const float* s; u16* d; int off;
  if (id < 65536)       { s = dW; d = dWb; off = id; }
  else if (id < 131072) { s = uW; d = uWb; off = id - 65536; }
  else if (id < 180224) { s = iW; d = iWb; off = id - 131072; }
  else                  { s = oW; d = oWb; off = id - 180224; }
  const float4 v = ((const float4*)s)[off];
  uint2 p; p.x = pk2(v.x, v.y); p.y = pk2(v.z, v.w);
  *(uint2*)&d[(size_t)off * 4] = p;
}

// ================= K1: down = gelu(x @ down_W^T + b) -> bf16 (+ fused tokT write) =================
__global__ __launch_bounds__(512) void k_down(const float* __restrict__ x,
                                              const u16* __restrict__ Wd,
                                              const float* __restrict__ bias,
                                              u16* __restrict__ out,
                                              u16* __restrict__ tokT)
{
  __shared__ u16 Ab[2][64 * 64];
  __shared__ u16 Bb[2][256 * 64];
  const int tid = threadIdx.x;
  const int lane = tid & 63, wave = tid >> 6;
  f32x4 acc[4][2] = {};
  const int m0 = blockIdx.x * 64;
  const int ar0 = tid >> 4;
  const int c4 = (tid & 15) * 4;

  f32x4 areg[2];
#pragma unroll
  for (int i = 0; i < 2; ++i)
    areg[i] = ntld4(&x[(size_t)(m0 + ar0 + 32 * i) * CC + c4]);
#pragma unroll
  for (int i = 0; i < 2; ++i) {
    const int r = ar0 + 32 * i;
    uint2 p; p.x = pk2(areg[i].x, areg[i].y); p.y = pk2(areg[i].z, areg[i].w);
    *(uint2*)((char*)Ab[0] + ((r * 128 + c4 * 2) ^ ((r & 7) << 4))) = p;
  }
  GLOAD_B4(Bb[0], &Wd[(size_t)r * CC + 0 + ce])
#pragma unroll
  for (int i = 0; i < 2; ++i)
    areg[i] = ntld4(&x[(size_t)(m0 + ar0 + 32 * i) * CC + 64 + c4]);

  for (int it = 0; it < 16; ++it) {
    const int cur = it & 1;
    if (it < 14) {
#pragma unroll
      for (int i = 0; i < 2; ++i) {
        const int r = ar0 + 32 * i;
        uint2 p; p.x = pk2(areg[i].x, areg[i].y); p.y = pk2(areg[i].z, areg[i].w);
        *(uint2*)((char*)Ab[cur ^ 1] + ((r * 128 + c4 * 2) ^ ((r & 7) << 4))) = p;
      }
      const int kx = (it + 2) * 64;
#pragma unroll
      for (int i = 0; i < 2; ++i)
        areg[i] = ntld4(&x[(size_t)(m0 + ar0 + 32 * i) * CC + kx + c4]);
      const int kb = (it + 1) * 64;
      GLOAD_B4(Bb[cur ^ 1], &Wd[(size_t)r * CC + kb + ce])
      asm volatile("s_waitcnt vmcnt(6) lgkmcnt(0)" ::: "memory");
    } else if (it == 14) {
#pragma unroll
      for (int i = 0; i < 2; ++i) {
        const int r = ar0 + 32 * i;
        uint2 p; p.x = pk2(areg[i].x, areg[i].y); p.y = pk2(areg[i].z, areg[i].w);
        *(uint2*)((char*)Ab[cur ^ 1] + ((r * 128 + c4 * 2) ^ ((r & 7) << 4))) = p;
      }
      GLOAD_B4(Bb[cur ^ 1], &Wd[(size_t)r * CC + 960 + ce])
      asm volatile("s_waitcnt vmcnt(4) lgkmcnt(0)" ::: "memory");
    } else {
      asm volatile("s_waitcnt vmcnt(0) lgkmcnt(0)" ::: "memory");
    }
    PIPE_BAR()
    MFMA_STEP64(Ab[cur], Bb[cur])
    PIPE_END()
  }
#pragma unroll
  for (int mi = 0; mi < 4; ++mi) {
#pragma unroll
    for (int ni = 0; ni < 2; ++ni) {
      const int col = wave * 32 + ni * 16 + (lane & 15);
      const float bv = bias[col];
      u16 vs[4];
#pragma unroll
      for (int r = 0; r < 4; ++r) {
        const int row = m0 + mi * 16 + (lane >> 4) * 4 + r;
        float v = acc[mi][ni][r] + bv;
        v = 0.5f * v * (1.f + erff(v * 0.7071067811865475f));
        vs[r] = f2bf(v);
        out[(size_t)row * DD + col] = vs[r];
      }
      const int row0 = m0 + mi * 16 + (lane >> 4) * 4;
      const int b = row0 / NN, rr = row0 - b * NN;
      if (rr >= PP) {
        const u64 pk = (u64)vs[0] | ((u64)vs[1] << 16) | ((u64)vs[2] << 32) | ((u64)vs[3] << 48);
        *(u64*)&tokT[((size_t)(b * DD + col)) * TT + (rr - PP)] = pk;
      }
    }
  }
}

// ================= K2: qkv (64-tile pipelined). grid (200, 3) =================
__global__ __launch_bounds__(512) void k_qkv(const u16* __restrict__ down,
                                             const u16* __restrict__ Wip,
                                             const float* __restrict__ bias,
                                             u16* __restrict__ qb,
                                             u16* __restrict__ kb,
                                             u16* __restrict__ vb)
{
  __shared__ u16 Ab[2][64 * 64];
  __shared__ u16 Bb[2][256 * 64];
  const int tid = threadIdx.x;
  const int lane = tid & 63, wave = tid >> 6;
  f32x4 acc[4][2] = {};
  const int m0 = blockIdx.x * 64;
  const int nt = blockIdx.y;

#define QKV_A(BUF, K0) GLOAD_A1(BUF, ({ const int m = m0 + r; const int b = m / PP; const int p = m - b * PP; \
                    &down[((size_t)(b * NN + p)) * DD + (K0) + ce]; }))
  QKV_A(Ab[0], 0)
  GLOAD_B4(Bb[0], &Wip[(size_t)(nt * 256 + r) * DD + 0 + ce])
  for (int it = 0; it < 4; ++it) {
    const int cur = it & 1;
    if (it < 3) {
      const int k0 = (it + 1) * 64;
      QKV_A(Ab[cur ^ 1], k0)
      GLOAD_B4(Bb[cur ^ 1], &Wip[(size_t)(nt * 256 + r) * DD + k0 + ce])
      PIPE_WAIT(5)
    } else { PIPE_WAIT(0) }
    PIPE_BAR()
    MFMA_STEP64(Ab[cur], Bb[cur])
    PIPE_END()
  }
#undef QKV_A
  u16* dst = (nt == 0) ? qb : ((nt == 1) ? kb : vb);
#pragma unroll
  for (int mi = 0; mi < 4; ++mi) {
#pragma unroll
    for (int ni = 0; ni < 2; ++ni) {
      const int n = wave * 32 + ni * 16 + (lane & 15);
      const float bv = bias[nt * 256 + n];
      const int h = n >> 6, dd = n & 63;
#pragma unroll
      for (int r = 0; r < 4; ++r) {
        const int m = m0 + mi * 16 + (lane >> 4) * 4 + r;
        const int b = m / PP, p = m - b * PP;
        dst[(((size_t)(b * HH + h)) * PP + p) * HDD + dd] = f2bf(acc[mi][ni][r] + bv);
      }
    }
  }
}

// ================= K3: self-attention MFMA, one block per (b,h), 8 waves =================
__global__ __launch_bounds__(512) void k_attn(const u16* __restrict__ qb,
                                              const u16* __restrict__ kb,
                                              const u16* __restrict__ vb,
                                              u16* __restrict__ sa)
{
  __shared__ u16 Ks[208 * 64];
  __shared__ u16 Vt[64 * 232];
  __shared__ u16 Pb[8 * 16 * 232];
  const int tid = threadIdx.x, lane = tid & 63, wave = tid >> 6;
  const int bh = blockIdx.x;
  const size_t kvbase = (size_t)bh * (PP * HDD);

  for (int it = 0; it < 7; ++it) {
    const int idx = tid + 512 * it;
    if (idx < 3200) {
      const int e = idx * 4;
      const int j = e >> 6, d = e & 63;
      const u64 kv = *(const u64*)&kb[kvbase + e];
      const int byt = (j * 128 + d * 2) ^ ((j & 7) << 4);
      *(u64*)((char*)Ks + byt) = kv;
      const u64 vv = *(const u64*)&vb[kvbase + e];
      const u16* vp = (const u16*)&vv;
#pragma unroll
      for (int w = 0; w < 4; ++w) Vt[(d + w) * 232 + j] = vp[w];
    }
  }
  if (tid < 128) {
    const int rr = 200 + (tid >> 4), c = (tid & 15) * 4;
    const int byt = (rr * 128 + c * 2) ^ ((rr & 7) << 4);
    *(u64*)((char*)Ks + byt) = 0ULL;
  }
  {
    const int d = tid >> 3, cg = tid & 7;
    *(u64*)&Vt[d * 232 + 200 + cg * 4] = 0ULL;
  }
  {
    u16* pw = Pb + wave * (16 * 232);
#pragma unroll
    for (int w = 0; w < 2; ++w) {
      const int idx = lane + 64 * w;
      if (idx < 96) {
        const int row = idx / 6, cg = idx - row * 6;
        *(u64*)&pw[row * 232 + 208 + cg * 4] = 0ULL;
      }
    }
  }
  __syncthreads();

  const int b_ = bh >> 2, h = bh & 3;
  const u16* qbase = qb + kvbase;
  u16* pw = Pb + wave * (16 * 232);

  for (int f = wave; f < 13; f += 8) {
    int qrow = f * 16 + (lane & 15); if (qrow > 199) qrow = 199;
    bf16x8 qa[2];
#pragma unroll
    for (int kk = 0; kk < 2; ++kk)
      qa[kk] = *(const bf16x8*)&qbase[(size_t)qrow * 64 + kk * 32 + (lane >> 4) * 8];

    f32x4 s[13];
#pragma unroll
    for (int nf = 0; nf < 13; ++nf) {
      const int R = nf * 16 + (lane & 15);
      f32x4 a = {};
#pragma unroll
      for (int kk = 0; kk < 2; ++kk) {
        const int byt = (R * 128 + (kk * 32 + (lane >> 4) * 8) * 2) ^ ((R & 7) << 4);
        const bf16x8 kf = *(const bf16x8*)((const char*)Ks + byt);
        a = __builtin_amdgcn_mfma_f32_16x16x32_bf16(qa[kk], kf, a, 0, 0, 0);
      }
      s[nf] = a;
    }
    float mx[4] = {-1e30f, -1e30f, -1e30f, -1e30f};
#pragma unroll
    for (int nf = 0; nf < 13; ++nf) {
      const int col = nf * 16 + (lane & 15);
#pragma unroll
      for (int r = 0; r < 4; ++r) {
        float v = (col < PP) ? s[nf][r] * 0.125f : -INFINITY;
        s[nf][r] = v;
        mx[r] = fmaxf(mx[r], v);
      }
    }
#pragma unroll
    for (int off = 1; off < 16; off <<= 1)
#pragma unroll
      for (int r = 0; r < 4; ++r) mx[r] = fmaxf(mx[r], __shfl_xor(mx[r], off));
    float sum[4] = {0.f, 0.f, 0.f, 0.f};
#pragma unroll
    for (int nf = 0; nf < 13; ++nf)
#pragma unroll
      for (int r = 0; r < 4; ++r) {
        const float e = expf(s[nf][r] - mx[r]);
        s[nf][r] = e;
        sum[r] += e;
      }
#pragma unroll
    for (int off = 1; off < 16; off <<= 1)
#pragma unroll
      for (int r = 0; r < 4; ++r) sum[r] += __shfl_xor(sum[r], off);
    float inv[4];
#pragma unroll
    for (int r = 0; r < 4; ++r) inv[r] = 1.f / sum[r];
#pragma unroll
    for (int nf = 0; nf < 13; ++nf) {
      const int col = nf * 16 + (lane & 15);
#pragma unroll
      for (int r = 0; r < 4; ++r) {
        const int row = (lane >> 4) * 4 + r;
        pw[row * 232 + col] = f2bf(s[nf][r] * inv[r]);
      }
    }
    f32x4 o[4] = {};
#pragma unroll
    for (int kk = 0; kk < 7; ++kk) {
      const bf16x8 pa = *(const bf16x8*)((const char*)pw +
                         ((lane & 15) * 232 + kk * 32 + (lane >> 4) * 8) * 2);
#pragma unroll
      for (int nf4 = 0; nf4 < 4; ++nf4) {
        const bf16x8 vv = *(const bf16x8*)((const char*)Vt +
                           (((lane & 15) + 16 * nf4) * 232 + kk * 32 + (lane >> 4) * 8) * 2);
        o[nf4] = __builtin_amdgcn_mfma_f32_16x16x32_bf16(pa, vv, o[nf4], 0, 0, 0);
      }
    }
#pragma unroll
    for (int nf4 = 0; nf4 < 4; ++nf4) {
      const int d = (lane & 15) + 16 * nf4;
#pragma unroll
      for (int r = 0; r < 4; ++r) {
        const int p = f * 16 + (lane >> 4) * 4 + r;
        if (p < PP)
          sa[((size_t)(b_ * PP + p)) * DD + h * HDD + d] = f2bf(o[nf4][r]);
      }
    }
  }
}

// ================= K4: fused oproj + scores + softmax + PV =================
// grid (BB, 4). LDS pool 128KB: Bb dbuf (64K) + scratch (64K: Ab-dbuf -> Afull -> Ph).
__global__ __launch_bounds__(512, 1) void k_fuse(const u16* __restrict__ A,
                                                 const u16* __restrict__ Wop,
                                                 const float* __restrict__ bias,
                                                 const u16* __restrict__ down,
                                                 const u16* __restrict__ tokT,
                                                 u16* __restrict__ pout)
{
  __shared__ __align__(16) char pool[131072];
  __shared__ float Mred[8][64];
  __shared__ float Lred[8][64];
  u16* Bb0 = (u16*)pool;
  u16* Bb1 = (u16*)(pool + 32768);
  u16* Ab0 = (u16*)(pool + 65536);
  u16* Ab1 = (u16*)(pool + 65536 + 8192);
  u16* Afull = (u16*)(pool + 65536);
  u16* Ph = (u16*)(pool + 65536);
  const int tid = threadIdx.x;
  const int lane = tid & 63, wave = tid >> 6;
  const int b = blockIdx.x, mh = blockIdx.y;
  const int m0 = mh * 64;

  // ---- phase 1: oproj GEMM ----
  f32x4 acc[4][2] = {};
#define FU_A(BUF, K0) GLOAD_A1(BUF, ({ int p = m0 + r; p = (p < PP) ? p : (PP - 1); \
                    &A[((size_t)(b * PP + p)) * DD + (K0) + ce]; }))
  FU_A(Ab0, 0)
  GLOAD_B4(Bb0, &Wop[(size_t)r * DD + 0 + ce])
  for (int it = 0; it < 4; ++it) {
    u16* Abc = (it & 1) ? Ab1 : Ab0;
    u16* Bbc = (it & 1) ? Bb1 : Bb0;
    u16* Abn = (it & 1) ? Ab0 : Ab1;
    u16* Bbn = (it & 1) ? Bb0 : Bb1;
    if (it < 3) {
      const int k0 = (it + 1) * 64;
      FU_A(Abn, k0)
      GLOAD_B4(Bbn, &Wop[(size_t)r * DD + k0 + ce])
      PIPE_WAIT(5)
    } else { PIPE_WAIT(0) }
    PIPE_BAR()
    MFMA_STEP64(Abc, Bbc)
    PIPE_END()
  }
#undef FU_A

  // prestage scores step-0 B (Bb0 free: last read was Bb1 at it=3)
  GLOAD_B4(Bb0, &down[((size_t)(b * NN + PP + r)) * DD + 0 + ce])

  // ---- phase 2: bias + bf16 -> Afull ----
#pragma unroll
  for (int mi = 0; mi < 4; ++mi) {
#pragma unroll
    for (int ni = 0; ni < 2; ++ni) {
      const int col = wave * 32 + ni * 16 + (lane & 15);
      const float bv = bias[col];
#pragma unroll
      for (int r = 0; r < 4; ++r) {
        const int row = mi * 16 + (lane >> 4) * 4 + r;
        *(u16*)((char*)Afull + ((row * 512 + col * 2) ^ ((row & 7) << 4))) =
            f2bf(acc[mi][ni][r] + bv);
      }
    }
  }
  LGKM_BAR()

  // ---- phase 3: scores GEMM, 16 steps ----
  f32x4 s4[4][4][2] = {};
#pragma unroll
  for (int st = 0; st < 16; ++st) {
    u16* Bbc = (st & 1) ? Bb1 : Bb0;
    u16* Bbn = (st & 1) ? Bb0 : Bb1;
    if (st < 15) {
      const int nx = st + 1;
      const int nt2 = nx >> 2, k02 = (nx & 3) * 64;
      GLOAD_B4(Bbn, &down[((size_t)(b * NN + PP + nt2 * 256 + r)) * DD + k02 + ce])
      PIPE_WAIT(4)
    } else { PIPE_WAIT(0) }
    PIPE_BAR()
    {
      const int k0s = (st & 3) * 64;
      MFMA_AF(s4[st >> 2], k0s, Bbc)
    }
    PIPE_END()
  }

  // prestage PV half0 step0 B (Bb0 free: last read Bb1 at st=15)
  GLOAD_B4(Bb0, &tokT[((size_t)(b * DD + r)) * TT + 0 + ce])

  // ---- phase 4: row softmax (unnormalized exp kept in s4) ----
  float mx[4][4];
#pragma unroll
  for (int mi = 0; mi < 4; ++mi)
#pragma unroll
    for (int r = 0; r < 4; ++r) mx[mi][r] = -1e30f;
#pragma unroll
  for (int nt = 0; nt < 4; ++nt)
#pragma unroll
    for (int mi = 0; mi < 4; ++mi)
#pragma unroll
      for (int ni = 0; ni < 2; ++ni)
#pragma unroll
        for (int r = 0; r < 4; ++r) {
          const float v = s4[nt][mi][ni][r] * 0.0625f;
          s4[nt][mi][ni][r] = v;
          mx[mi][r] = fmaxf(mx[mi][r], v);
        }
#pragma unroll
  for (int off = 1; off < 16; off <<= 1)
#pragma unroll
    for (int mi = 0; mi < 4; ++mi)
#pragma unroll
      for (int r = 0; r < 4; ++r) mx[mi][r] = fmaxf(mx[mi][r], __shfl_xor(mx[mi][r], off));
  if ((lane & 15) == 0) {
#pragma unroll
    for (int mi = 0; mi < 4; ++mi)
#pragma unroll
      for (int r = 0; r < 4; ++r)
        Mred[wave][mi * 16 + (lane >> 4) * 4 + r] = mx[mi][r];
  }
  LGKM_BAR()
  float M[4][4];
#pragma unroll
  for (int mi = 0; mi < 4; ++mi)
#pragma unroll
    for (int r = 0; r < 4; ++r) {
      const int row = mi * 16 + (lane >> 4) * 4 + r;
      float m = Mred[0][row];
#pragma unroll
      for (int w = 1; w < 8; ++w) m = fmaxf(m, Mred[w][row]);
      M[mi][r] = m;
    }
  float l[4][4];
#pragma unroll
  for (int mi = 0; mi < 4; ++mi)
#pragma unroll
    for (int r = 0; r < 4; ++r) l[mi][r] = 0.f;
#pragma unroll
  for (int nt = 0; nt < 4; ++nt)
#pragma unroll
    for (int mi = 0; mi < 4; ++mi)
#pragma unroll
      for (int ni = 0; ni < 2; ++ni)
#pragma unroll
        for (int r = 0; r < 4; ++r) {
          const float e = __expf(s4[nt][mi][ni][r] - M[mi][r]);
          s4[nt][mi][ni][r] = e;
          l[mi][r] += e;
        }
#pragma unroll
  for (int off = 1; off < 16; off <<= 1)
#pragma unroll
    for (int mi = 0; mi < 4; ++mi)
#pragma unroll
      for (int r = 0; r < 4; ++r) l[mi][r] += __shfl_xor(l[mi][r], off);
  if ((lane & 15) == 0) {
#pragma unroll
    for (int mi = 0; mi < 4; ++mi)
#pragma unroll
      for (int r = 0; r < 4; ++r)
        Lred[wave][mi * 16 + (lane >> 4) * 4 + r] = l[mi][r];
  }
  LGKM_BAR()
  float inv[4][4];
#pragma unroll
  for (int mi = 0; mi < 4; ++mi)
#pragma unroll
    for (int r = 0; r < 4; ++r) {
      const int row = mi * 16 + (lane >> 4) * 4 + r;
      float t = 0.f;
#pragma unroll
      for (int w = 0; w < 8; ++w) t += Lred[w][row];
      inv[mi][r] = 1.f / t;
    }

  // ---- phase 5: PV in two t-halves (Ph = 64 x 512 unnormalized P) ----
  f32x4 o[4][2] = {};
#define WRITE_P(NT0) \
  _Pragma("unroll") \
  for (int q = 0; q < 2; ++q) \
    _Pragma("unroll") \
    for (int mi = 0; mi < 4; ++mi) \
      _Pragma("unroll") \
      for (int ni = 0; ni < 2; ++ni) { \
        const int tl = q * 256 + wave * 32 + ni * 16 + (lane & 15); \
        _Pragma("unroll") \
        for (int r = 0; r < 4; ++r) { \
          const int row = mi * 16 + (lane >> 4) * 4 + r; \
          *(u16*)((char*)Ph + ((row * 1024 + tl * 2) ^ ((row & 7) << 4))) = \
              f2bf(s4[(NT0) + q][mi][ni][r]); \
        } \
      }

  WRITE_P(0)
  LGKM_BAR()
#pragma unroll
  for (int st = 0; st < 8; ++st) {
    u16* Bbc = (st & 1) ? Bb1 : Bb0;
    u16* Bbn = (st & 1) ? Bb0 : Bb1;
    if (st < 7) {
      GLOAD_B4(Bbn, &tokT[((size_t)(b * DD + r)) * TT + (st + 1) * 64 + ce])
      PIPE_WAIT(4)
    } else {
      // prefetch half-1 step-0 into Bbn (= Bb0)
      GLOAD_B4(Bbn, &tokT[((size_t)(b * DD + r)) * TT + 512 + ce])
      PIPE_WAIT(4)
    }
    PIPE_BAR()
    MFMA_PV(o, st * 64, Bbc)
    PIPE_END()
  }
  WRITE_P(2)
  LGKM_BAR()
#pragma unroll
  for (int st = 0; st < 8; ++st) {
    u16* Bbc = (st & 1) ? Bb1 : Bb0;
    u16* Bbn = (st & 1) ? Bb0 : Bb1;
    if (st < 7) {
      GLOAD_B4(Bbn, &tokT[((size_t)(b * DD + r)) * TT + 512 + (st + 1) * 64 + ce])
      PIPE_WAIT(4)
    } else { PIPE_WAIT(0) }
    PIPE_BAR()
    MFMA_PV(o, st * 64, Bbc)
    PIPE_END()
  }
#undef WRITE_P

  // ---- epilogue: pout = o * inv ----
#pragma unroll
  for (int mi = 0; mi < 4; ++mi) {
#pragma unroll
    for (int ni = 0; ni < 2; ++ni) {
      const int e = wave * 32 + ni * 16 + (lane & 15);
#pragma unroll
      for (int r = 0; r < 4; ++r) {
        const int p = m0 + mi * 16 + (lane >> 4) * 4 + r;
        if (p < PP)
          pout[((size_t)(b * PP + p)) * DD + e] = f2bf(o[mi][ni][r] * inv[mi][r]);
      }
    }
  }
}

// ================= K7: out = gate * (combined @ up_W^T + b), NT stores =================
__global__ __launch_bounds__(512) void k_up(const u16* __restrict__ poutbf,
                                            const u16* __restrict__ down,
                                            const u16* __restrict__ Wu,
                                            const float* __restrict__ bias,
                                            const float* __restrict__ gate,
                                            float* __restrict__ out)
{
  __shared__ u16 Ab[2][64 * 64];
  __shared__ u16 Bb[2][256 * 64];
  const int tid = threadIdx.x;
  const int lane = tid & 63, wave = tid >> 6;
  f32x4 acc[4][2] = {};
  const int m0 = blockIdx.x * 64;
  const int n0 = blockIdx.y * 256;

#define UP_A(BUF, K0) GLOAD_A1(BUF, ({ const int m = m0 + r; const int b = m / NN; const int rr = m - b * NN; \
                     const u16* base = (rr < PP) ? &poutbf[((size_t)(b * PP + rr)) * DD] \
                                                 : &down[((size_t)(b * NN + rr)) * DD]; \
                     base + (K0) + ce; }))
  UP_A(Ab[0], 0)
  GLOAD_B4(Bb[0], &Wu[(size_t)(n0 + r) * DD + 0 + ce])
  for (int it = 0; it < 4; ++it) {
    const int cur = it & 1;
    if (it < 3) {
      const int k0 = (it + 1) * 64;
      UP_A(Ab[cur ^ 1], k0)
      GLOAD_B4(Bb[cur ^ 1], &Wu[(size_t)(n0 + r) * DD + k0 + ce])
      PIPE_WAIT(5)
    } else { PIPE_WAIT(0) }
    PIPE_BAR()
    MFMA_STEP64(Ab[cur], Bb[cur])
    PIPE_END()
  }
#undef UP_A
  const float g = gate[0];
#pragma unroll
  for (int mi = 0; mi < 4; ++mi) {
#pragma unroll
    for (int ni = 0; ni < 2; ++ni) {
      const int col = n0 + wave * 32 + ni * 16 + (lane & 15);
      const float bv = bias[col];
#pragma unroll
      for (int r = 0; r < 4; ++r) {
        const int row = m0 + mi * 16 + (lane >> 4) * 4 + r;
        __builtin_nontemporal_store((acc[mi][ni][r] + bv) * g, &out[(size_t)row * CC + col]);
      }
    }
  }
}

extern "C" void kernel_launch(void* const* d_in, const int* in_sizes, int n_in,
                              void* d_out, int out_size, void* d_ws, size_t ws_size,
                              hipStream_t stream) {
  const float* x          = (const float*)d_in[0];
  const float* down_W     = (const float*)d_in[1];
  const float* down_b     = (const float*)d_in[2];
  const float* up_W       = (const float*)d_in[3];
  const float* up_b       = (const float*)d_in[4];
  const float* in_proj_W  = (const float*)d_in[5];
  const float* in_proj_b  = (const float*)d_in[6];
  const float* out_proj_W = (const float*)d_in[7];
  const float* out_proj_b = (const float*)d_in[8];
  const float* gate       = (const float*)d_in[9];
  float* out = (float*)d_out;

  char* wsb = (char*)d_ws;
  u16* down_bf = (u16*)(wsb + B_DOWN);
  u16* tokT    = (u16*)(wsb + B_TOKT);
  u16* qb      = (u16*)(wsb + B_QB);
  u16* kb      = (u16*)(wsb + B_KB);
  u16* vb      = (u16*)(wsb + B_VB);
  u16* sa_bf   = (u16*)(wsb + B_SA);
  u16* poutbf  = (u16*)(wsb + B_POUTBF);
  u16* Wd  = (u16*)(wsb + B_WD);
  u16* Wu  = (u16*)(wsb + B_WU);
  u16* Wip = (u16*)(wsb + B_WIP);
  u16* Wop = (u16*)(wsb + B_WOP);

  k_castw<<<dim3(768), 256, 0, stream>>>(down_W, up_W, in_proj_W, out_proj_W, Wd, Wu, Wip, Wop);
  k_down<<<dim3((BB * NN) / 64), 512, 0, stream>>>(x, Wd, down_b, down_bf, tokT);
  k_qkv<<<dim3(200, 3), 512, 0, stream>>>(down_bf, Wip, in_proj_b, qb, kb, vb);
  k_attn<<<dim3(BB * HH), 512, 0, stream>>>(qb, kb, vb, sa_bf);
  k_fuse<<<dim3(BB, 4), 512, 0, stream>>>(sa_bf, Wop, out_proj_b, down_bf, tokT, poutbf);
  k_up<<<dim3((BB * NN) / 64, CC / 256), 512, 0, stream>>>(poutbf, down_bf, Wu, up_b, gate, out);
}

// Round 14
// 303.445 us; speedup vs baseline: 1.0490x; 1.0490x over previous
//
#include <hip/hip_runtime.h>
#include <math.h>

#define BB 64
#define NN 1224
#define CC 1024
#define DD 256
#define PP 200
#define TT 1024
#define HH 4
#define HDD 64

typedef __attribute__((ext_vector_type(8))) short bf16x8;
typedef __attribute__((ext_vector_type(4))) float f32x4;
typedef unsigned short u16;
typedef unsigned long long u64;

__device__ __forceinline__ u16 f2bf(float f) {
  union { float f; unsigned int u; } v; v.f = f;
  unsigned int r = v.u + 0x7FFF + ((v.u >> 16) & 1);
  return (u16)(r >> 16);
}
__device__ __forceinline__ float bf2f(u16 h) {
  union { unsigned int u; float f; } v; v.u = ((unsigned int)h) << 16;
  return v.f;
}
__device__ __forceinline__ unsigned int pk2(float a, float b) {
  return (unsigned int)f2bf(a) | ((unsigned int)f2bf(b) << 16);
}
__device__ __forceinline__ void gload16(const void* g, void* l) {
  __builtin_amdgcn_global_load_lds(
      (const __attribute__((address_space(1))) void*)g,
      (__attribute__((address_space(3))) void*)l, 16, 0, 0);
}
__device__ __forceinline__ f32x4 ntld4(const float* p) {
  return __builtin_nontemporal_load((const f32x4*)p);
}

// ---------------- workspace layout (bytes) ----------------
static const size_t SZ_DOWN = (size_t)BB * NN * DD * 2;
static const size_t SZ_TOKT = (size_t)BB * DD * TT * 2;
static const size_t SZ_Q    = (size_t)BB * HH * PP * HDD * 2;
static const size_t SZ_SCORES = (size_t)BB * PP * TT * 2;

static const size_t B_DOWN   = 0;
static const size_t B_TOKT   = B_DOWN + SZ_DOWN;
static const size_t B_POOL   = B_TOKT + SZ_TOKT;
static const size_t B_QB     = B_POOL;
static const size_t B_KB     = B_QB + SZ_Q;
static const size_t B_VB     = B_KB + SZ_Q;
static const size_t B_SA     = B_VB + SZ_Q;
static const size_t B_SA2    = B_SA + SZ_Q;
static const size_t B_POUTBF = B_SA2;               // pout tile (sa2 never materialized)
static const size_t B_SCORES = B_SA2 + SZ_Q;
static const size_t B_PBF    = B_SCORES;            // P: does NOT alias sa
static const size_t B_W      = B_SCORES + SZ_SCORES * 2;
static const size_t B_WD     = B_W;
static const size_t B_WU     = B_WD + 524288;
static const size_t B_WIP    = B_WU + 524288;
static const size_t B_WOP    = B_WIP + 393216;

// ---------------- 64x256-tile pieces ----------------
#define MFMA_STEP64(Ab, Bb) \
  _Pragma("unroll") \
  for (int kk = 0; kk < 64; kk += 32) { \
    bf16x8 af[4], bfr[2]; \
    _Pragma("unroll") \
    for (int mi = 0; mi < 4; ++mi) { \
      const int R = mi * 16 + (lane & 15); \
      const int byt = (R * 128 + (kk + (lane >> 4) * 8) * 2) ^ ((R & 7) << 4); \
      af[mi] = *(const bf16x8*)((const char*)(Ab) + byt); \
    } \
    _Pragma("unroll") \
    for (int ni = 0; ni < 2; ++ni) { \
      const int R = wave * 32 + ni * 16 + (lane & 15); \
      const int byt = (R * 128 + (kk + (lane >> 4) * 8) * 2) ^ ((R & 7) << 4); \
      bfr[ni] = *(const bf16x8*)((const char*)(Bb) + byt); \
    } \
    _Pragma("unroll") \
    for (int mi = 0; mi < 4; ++mi) \
      _Pragma("unroll") \
      for (int ni = 0; ni < 2; ++ni) \
        acc[mi][ni] = __builtin_amdgcn_mfma_f32_16x16x32_bf16(af[mi], bfr[ni], acc[mi][ni], 0, 0, 0); \
  }

// A from persistent LDS Afull (64 x 256, pitch 512B, swizzled)
#define MFMA_AF(SACC, K0, Bbuf) \
  _Pragma("unroll") \
  for (int kk = 0; kk < 64; kk += 32) { \
    bf16x8 af[4], bfr[2]; \
    _Pragma("unroll") \
    for (int mi = 0; mi < 4; ++mi) { \
      const int R = mi * 16 + (lane & 15); \
      const int byt = (R * 512 + ((K0) + kk + (lane >> 4) * 8) * 2) ^ ((R & 7) << 4); \
      af[mi] = *(const bf16x8*)((const char*)Afull + byt); \
    } \
    _Pragma("unroll") \
    for (int ni = 0; ni < 2; ++ni) { \
      const int R = wave * 32 + ni * 16 + (lane & 15); \
      const int byt = (R * 128 + (kk + (lane >> 4) * 8) * 2) ^ ((R & 7) << 4); \
      bfr[ni] = *(const bf16x8*)((const char*)(Bbuf) + byt); \
    } \
    _Pragma("unroll") \
    for (int mi = 0; mi < 4; ++mi) \
      _Pragma("unroll") \
      for (int ni = 0; ni < 2; ++ni) \
        SACC[mi][ni] = __builtin_amdgcn_mfma_f32_16x16x32_bf16(af[mi], bfr[ni], SACC[mi][ni], 0, 0, 0); \
  }

#define GLOAD_A1(Ab, SRC) \
  { \
    const int L = wave * 1024 + lane * 16; \
    const int r = L >> 7; \
    const int ce = ((L & 127) ^ ((r & 7) << 4)) >> 1; \
    gload16((SRC), (char*)(Ab) + wave * 1024); \
  }

#define GLOAD_B4(Bb, SRC) \
  _Pragma("unroll") \
  for (int ii = 0; ii < 4; ++ii) { \
    const int slot = wave * 4 + ii; \
    const int L = slot * 1024 + lane * 16; \
    const int r = L >> 7; \
    const int ce = ((L & 127) ^ ((r & 7) << 4)) >> 1; \
    gload16((SRC), (char*)(Bb) + slot * 1024); \
  }

#define PIPE_WAIT(N) asm volatile("s_waitcnt vmcnt(" #N ")" ::: "memory");
#define PIPE_BAR() \
  __builtin_amdgcn_s_barrier(); \
  __builtin_amdgcn_sched_barrier(0);
#define PIPE_END() \
  asm volatile("s_waitcnt lgkmcnt(0)" ::: "memory"); \
  __builtin_amdgcn_s_barrier(); \
  __builtin_amdgcn_sched_barrier(0);

// ================= K0: cast all weights to bf16 =================
__global__ __launch_bounds__(256) void k_castw(const float* __restrict__ dW,
                                               const float* __restrict__ uW,
                                               const float* __restrict__ iW,
                                               const float* __restrict__ oW,
                                               u16* __restrict__ dWb, u16* __restrict__ uWb,
                                               u16* __restrict__ iWb, u16* __restrict__ oWb)
{
  const int id = blockIdx.x * 256 + threadIdx.x;
  const float* s; u16* d; int off;
  if (id < 65536)       { s = dW; d = dWb; off = id; }
  else if (id < 131072) { s = uW; d = uWb; off = id - 65536; }
  else if (id < 180224) { s = iW; d = iWb; off = id - 131072; }
  else                  { s = oW; d = oWb; off = id - 180224; }
  const float4 v = ((const float4*)s)[off];
  uint2 p; p.x = pk2(v.x, v.y); p.y = pk2(v.z, v.w);
  *(uint2*)&d[(size_t)off * 4] = p;
}

// ================= K1: down = gelu(x @ down_W^T + b) -> bf16 (+ fused tokT write) =================
__global__ __launch_bounds__(512) void k_down(const float* __restrict__ x,
                                              const u16* __restrict__ Wd,
                                              const float* __restrict__ bias,
                                              u16* __restrict__ out,
                                              u16* __restrict__ tokT)
{
  __shared__ u16 Ab[2][64 * 64];
  __shared__ u16 Bb[2][256 * 64];
  const int tid = threadIdx.x;
  const int lane = tid & 63, wave = tid >> 6;
  f32x4 acc[4][2] = {};
  const int m0 = blockIdx.x * 64;
  const int ar0 = tid >> 4;
  const int c4 = (tid & 15) * 4;

  f32x4 areg[2];
#pragma unroll
  for (int i = 0; i < 2; ++i)
    areg[i] = ntld4(&x[(size_t)(m0 + ar0 + 32 * i) * CC + c4]);
#pragma unroll
  for (int i = 0; i < 2; ++i) {
    const int r = ar0 + 32 * i;
    uint2 p; p.x = pk2(areg[i].x, areg[i].y); p.y = pk2(areg[i].z, areg[i].w);
    *(uint2*)((char*)Ab[0] + ((r * 128 + c4 * 2) ^ ((r & 7) << 4))) = p;
  }
  GLOAD_B4(Bb[0], &Wd[(size_t)r * CC + 0 + ce])
#pragma unroll
  for (int i = 0; i < 2; ++i)
    areg[i] = ntld4(&x[(size_t)(m0 + ar0 + 32 * i) * CC + 64 + c4]);

  for (int it = 0; it < 16; ++it) {
    const int cur = it & 1;
    if (it < 14) {
#pragma unroll
      for (int i = 0; i < 2; ++i) {
        const int r = ar0 + 32 * i;
        uint2 p; p.x = pk2(areg[i].x, areg[i].y); p.y = pk2(areg[i].z, areg[i].w);
        *(uint2*)((char*)Ab[cur ^ 1] + ((r * 128 + c4 * 2) ^ ((r & 7) << 4))) = p;
      }
      const int kx = (it + 2) * 64;
#pragma unroll
      for (int i = 0; i < 2; ++i)
        areg[i] = ntld4(&x[(size_t)(m0 + ar0 + 32 * i) * CC + kx + c4]);
      const int kb = (it + 1) * 64;
      GLOAD_B4(Bb[cur ^ 1], &Wd[(size_t)r * CC + kb + ce])
      asm volatile("s_waitcnt vmcnt(6) lgkmcnt(0)" ::: "memory");
    } else if (it == 14) {
#pragma unroll
      for (int i = 0; i < 2; ++i) {
        const int r = ar0 + 32 * i;
        uint2 p; p.x = pk2(areg[i].x, areg[i].y); p.y = pk2(areg[i].z, areg[i].w);
        *(uint2*)((char*)Ab[cur ^ 1] + ((r * 128 + c4 * 2) ^ ((r & 7) << 4))) = p;
      }
      GLOAD_B4(Bb[cur ^ 1], &Wd[(size_t)r * CC + 960 + ce])
      asm volatile("s_waitcnt vmcnt(4) lgkmcnt(0)" ::: "memory");
    } else {
      asm volatile("s_waitcnt vmcnt(0) lgkmcnt(0)" ::: "memory");
    }
    PIPE_BAR()
    MFMA_STEP64(Ab[cur], Bb[cur])
    PIPE_END()
  }
#pragma unroll
  for (int mi = 0; mi < 4; ++mi) {
#pragma unroll
    for (int ni = 0; ni < 2; ++ni) {
      const int col = wave * 32 + ni * 16 + (lane & 15);
      const float bv = bias[col];
      u16 vs[4];
#pragma unroll
      for (int r = 0; r < 4; ++r) {
        const int row = m0 + mi * 16 + (lane >> 4) * 4 + r;
        float v = acc[mi][ni][r] + bv;
        v = 0.5f * v * (1.f + erff(v * 0.7071067811865475f));
        vs[r] = f2bf(v);
        out[(size_t)row * DD + col] = vs[r];
      }
      const int row0 = m0 + mi * 16 + (lane >> 4) * 4;
      const int b = row0 / NN, rr = row0 - b * NN;
      if (rr >= PP) {
        const u64 pk = (u64)vs[0] | ((u64)vs[1] << 16) | ((u64)vs[2] << 32) | ((u64)vs[3] << 48);
        *(u64*)&tokT[((size_t)(b * DD + col)) * TT + (rr - PP)] = pk;
      }
    }
  }
}

// ================= K2: qkv (64-tile pipelined). grid (200, 3) =================
__global__ __launch_bounds__(512) void k_qkv(const u16* __restrict__ down,
                                             const u16* __restrict__ Wip,
                                             const float* __restrict__ bias,
                                             u16* __restrict__ qb,
                                             u16* __restrict__ kb,
                                             u16* __restrict__ vb)
{
  __shared__ u16 Ab[2][64 * 64];
  __shared__ u16 Bb[2][256 * 64];
  const int tid = threadIdx.x;
  const int lane = tid & 63, wave = tid >> 6;
  f32x4 acc[4][2] = {};
  const int m0 = blockIdx.x * 64;
  const int nt = blockIdx.y;

#define QKV_A(BUF, K0) GLOAD_A1(BUF, ({ const int m = m0 + r; const int b = m / PP; const int p = m - b * PP; \
                    &down[((size_t)(b * NN + p)) * DD + (K0) + ce]; }))
  QKV_A(Ab[0], 0)
  GLOAD_B4(Bb[0], &Wip[(size_t)(nt * 256 + r) * DD + 0 + ce])
  for (int it = 0; it < 4; ++it) {
    const int cur = it & 1;
    if (it < 3) {
      const int k0 = (it + 1) * 64;
      QKV_A(Ab[cur ^ 1], k0)
      GLOAD_B4(Bb[cur ^ 1], &Wip[(size_t)(nt * 256 + r) * DD + k0 + ce])
      PIPE_WAIT(5)
    } else { PIPE_WAIT(0) }
    PIPE_BAR()
    MFMA_STEP64(Ab[cur], Bb[cur])
    PIPE_END()
  }
#undef QKV_A
  u16* dst = (nt == 0) ? qb : ((nt == 1) ? kb : vb);
#pragma unroll
  for (int mi = 0; mi < 4; ++mi) {
#pragma unroll
    for (int ni = 0; ni < 2; ++ni) {
      const int n = wave * 32 + ni * 16 + (lane & 15);
      const float bv = bias[nt * 256 + n];
      const int h = n >> 6, dd = n & 63;
#pragma unroll
      for (int r = 0; r < 4; ++r) {
        const int m = m0 + mi * 16 + (lane >> 4) * 4 + r;
        const int b = m / PP, p = m - b * PP;
        dst[(((size_t)(b * HH + h)) * PP + p) * HDD + dd] = f2bf(acc[mi][ni][r] + bv);
      }
    }
  }
}

// ================= K3: self-attention MFMA, one block per (b,h), 8 waves =================
__global__ __launch_bounds__(512) void k_attn(const u16* __restrict__ qb,
                                              const u16* __restrict__ kb,
                                              const u16* __restrict__ vb,
                                              u16* __restrict__ sa)
{
  __shared__ u16 Ks[208 * 64];
  __shared__ u16 Vt[64 * 232];
  __shared__ u16 Pb[8 * 16 * 232];
  const int tid = threadIdx.x, lane = tid & 63, wave = tid >> 6;
  const int bh = blockIdx.x;
  const size_t kvbase = (size_t)bh * (PP * HDD);

  for (int it = 0; it < 7; ++it) {
    const int idx = tid + 512 * it;
    if (idx < 3200) {
      const int e = idx * 4;
      const int j = e >> 6, d = e & 63;
      const u64 kv = *(const u64*)&kb[kvbase + e];
      const int byt = (j * 128 + d * 2) ^ ((j & 7) << 4);
      *(u64*)((char*)Ks + byt) = kv;
      const u64 vv = *(const u64*)&vb[kvbase + e];
      const u16* vp = (const u16*)&vv;
#pragma unroll
      for (int w = 0; w < 4; ++w) Vt[(d + w) * 232 + j] = vp[w];
    }
  }
  if (tid < 128) {
    const int rr = 200 + (tid >> 4), c = (tid & 15) * 4;
    const int byt = (rr * 128 + c * 2) ^ ((rr & 7) << 4);
    *(u64*)((char*)Ks + byt) = 0ULL;
  }
  {
    const int d = tid >> 3, cg = tid & 7;
    *(u64*)&Vt[d * 232 + 200 + cg * 4] = 0ULL;
  }
  {
    u16* pw = Pb + wave * (16 * 232);
#pragma unroll
    for (int w = 0; w < 2; ++w) {
      const int idx = lane + 64 * w;
      if (idx < 96) {
        const int row = idx / 6, cg = idx - row * 6;
        *(u64*)&pw[row * 232 + 208 + cg * 4] = 0ULL;
      }
    }
  }
  __syncthreads();

  const int b_ = bh >> 2, h = bh & 3;
  const u16* qbase = qb + kvbase;
  u16* pw = Pb + wave * (16 * 232);

  for (int f = wave; f < 13; f += 8) {
    int qrow = f * 16 + (lane & 15); if (qrow > 199) qrow = 199;
    bf16x8 qa[2];
#pragma unroll
    for (int kk = 0; kk < 2; ++kk)
      qa[kk] = *(const bf16x8*)&qbase[(size_t)qrow * 64 + kk * 32 + (lane >> 4) * 8];

    f32x4 s[13];
#pragma unroll
    for (int nf = 0; nf < 13; ++nf) {
      const int R = nf * 16 + (lane & 15);
      f32x4 a = {};
#pragma unroll
      for (int kk = 0; kk < 2; ++kk) {
        const int byt = (R * 128 + (kk * 32 + (lane >> 4) * 8) * 2) ^ ((R & 7) << 4);
        const bf16x8 kf = *(const bf16x8*)((const char*)Ks + byt);
        a = __builtin_amdgcn_mfma_f32_16x16x32_bf16(qa[kk], kf, a, 0, 0, 0);
      }
      s[nf] = a;
    }
    float mx[4] = {-1e30f, -1e30f, -1e30f, -1e30f};
#pragma unroll
    for (int nf = 0; nf < 13; ++nf) {
      const int col = nf * 16 + (lane & 15);
#pragma unroll
      for (int r = 0; r < 4; ++r) {
        float v = (col < PP) ? s[nf][r] * 0.125f : -INFINITY;
        s[nf][r] = v;
        mx[r] = fmaxf(mx[r], v);
      }
    }
#pragma unroll
    for (int off = 1; off < 16; off <<= 1)
#pragma unroll
      for (int r = 0; r < 4; ++r) mx[r] = fmaxf(mx[r], __shfl_xor(mx[r], off));
    float sum[4] = {0.f, 0.f, 0.f, 0.f};
#pragma unroll
    for (int nf = 0; nf < 13; ++nf)
#pragma unroll
      for (int r = 0; r < 4; ++r) {
        const float e = expf(s[nf][r] - mx[r]);
        s[nf][r] = e;
        sum[r] += e;
      }
#pragma unroll
    for (int off = 1; off < 16; off <<= 1)
#pragma unroll
      for (int r = 0; r < 4; ++r) sum[r] += __shfl_xor(sum[r], off);
    float inv[4];
#pragma unroll
    for (int r = 0; r < 4; ++r) inv[r] = 1.f / sum[r];
#pragma unroll
    for (int nf = 0; nf < 13; ++nf) {
      const int col = nf * 16 + (lane & 15);
#pragma unroll
      for (int r = 0; r < 4; ++r) {
        const int row = (lane >> 4) * 4 + r;
        pw[row * 232 + col] = f2bf(s[nf][r] * inv[r]);
      }
    }
    f32x4 o[4] = {};
#pragma unroll
    for (int kk = 0; kk < 7; ++kk) {
      const bf16x8 pa = *(const bf16x8*)((const char*)pw +
                         ((lane & 15) * 232 + kk * 32 + (lane >> 4) * 8) * 2);
#pragma unroll
      for (int nf4 = 0; nf4 < 4; ++nf4) {
        const bf16x8 vv = *(const bf16x8*)((const char*)Vt +
                           (((lane & 15) + 16 * nf4) * 232 + kk * 32 + (lane >> 4) * 8) * 2);
        o[nf4] = __builtin_amdgcn_mfma_f32_16x16x32_bf16(pa, vv, o[nf4], 0, 0, 0);
      }
    }
#pragma unroll
    for (int nf4 = 0; nf4 < 4; ++nf4) {
      const int d = (lane & 15) + 16 * nf4;
#pragma unroll
      for (int r = 0; r < 4; ++r) {
        const int p = f * 16 + (lane >> 4) * 4 + r;
        if (p < PP)
          sa[((size_t)(b_ * PP + p)) * DD + h * HDD + d] = f2bf(o[nf4][r]);
      }
    }
  }
}

// ================= K4: fused oproj + scores + softmax =================
__global__ __launch_bounds__(512, 2) void k_fuse(const u16* __restrict__ A,
                                                 const u16* __restrict__ Wop,
                                                 const float* __restrict__ bias,
                                                 const u16* __restrict__ down,
                                                 u16* __restrict__ pbf)
{
  __shared__ u16 Ab[2][64 * 64];
  __shared__ u16 Bb[2][256 * 64];
  __shared__ u16 Afull[64 * 256];
  __shared__ float Mred[8][64];
  __shared__ float Lred[8][64];
  const int tid = threadIdx.x;
  const int lane = tid & 63, wave = tid >> 6;
  const int b = blockIdx.x, mh = blockIdx.y;
  const int m0 = mh * 64;

  // ---- phase 1: oproj GEMM ----
  f32x4 acc[4][2] = {};
#define FU_A(BUF, K0) GLOAD_A1(BUF, ({ int p = m0 + r; p = (p < PP) ? p : (PP - 1); \
                    &A[((size_t)(b * PP + p)) * DD + (K0) + ce]; }))
  FU_A(Ab[0], 0)
  GLOAD_B4(Bb[0], &Wop[(size_t)r * DD + 0 + ce])
  for (int it = 0; it < 4; ++it) {
    const int cur = it & 1;
    if (it < 3) {
      const int k0 = (it + 1) * 64;
      FU_A(Ab[cur ^ 1], k0)
      GLOAD_B4(Bb[cur ^ 1], &Wop[(size_t)r * DD + k0 + ce])
      PIPE_WAIT(5)
    } else { PIPE_WAIT(0) }
    PIPE_BAR()
    MFMA_STEP64(Ab[cur], Bb[cur])
    PIPE_END()
  }
#undef FU_A

  // issue phase-3 prologue B stage early
  GLOAD_B4(Bb[0], &down[((size_t)(b * NN + PP + r)) * DD + 0 + ce])

  // ---- phase 2: bias + bf16 -> Afull ----
#pragma unroll
  for (int mi = 0; mi < 4; ++mi) {
#pragma unroll
    for (int ni = 0; ni < 2; ++ni) {
      const int col = wave * 32 + ni * 16 + (lane & 15);
      const float bv = bias[col];
#pragma unroll
      for (int r = 0; r < 4; ++r) {
        const int row = mi * 16 + (lane >> 4) * 4 + r;
        *(u16*)((char*)Afull + ((row * 512 + col * 2) ^ ((row & 7) << 4))) =
            f2bf(acc[mi][ni][r] + bv);
      }
    }
  }
  __syncthreads();

  // ---- phase 3: scores GEMM, 16 steps ----
  f32x4 s4[4][4][2] = {};
#pragma unroll
  for (int st = 0; st < 16; ++st) {
    const int cur = st & 1;
    if (st < 15) {
      const int nx = st + 1;
      const int nt2 = nx >> 2, k02 = (nx & 3) * 64;
      GLOAD_B4(Bb[cur ^ 1], &down[((size_t)(b * NN + PP + nt2 * 256 + r)) * DD + k02 + ce])
      PIPE_WAIT(4)
    } else { PIPE_WAIT(0) }
    PIPE_BAR()
    {
      const int k0s = (st & 3) * 64;
      MFMA_AF(s4[st >> 2], k0s, Bb[cur])
    }
    PIPE_END()
  }

  // ---- phase 4: row softmax ----
  float mx[4][4];
#pragma unroll
  for (int mi = 0; mi < 4; ++mi)
#pragma unroll
    for (int r = 0; r < 4; ++r) mx[mi][r] = -1e30f;
#pragma unroll
  for (int nt = 0; nt < 4; ++nt)
#pragma unroll
    for (int mi = 0; mi < 4; ++mi)
#pragma unroll
      for (int ni = 0; ni < 2; ++ni)
#pragma unroll
        for (int r = 0; r < 4; ++r) {
          const float v = s4[nt][mi][ni][r] * 0.0625f;
          s4[nt][mi][ni][r] = v;
          mx[mi][r] = fmaxf(mx[mi][r], v);
        }
#pragma unroll
  for (int off = 1; off < 16; off <<= 1)
#pragma unroll
    for (int mi = 0; mi < 4; ++mi)
#pragma unroll
      for (int r = 0; r < 4; ++r) mx[mi][r] = fmaxf(mx[mi][r], __shfl_xor(mx[mi][r], off));
  if ((lane & 15) == 0) {
#pragma unroll
    for (int mi = 0; mi < 4; ++mi)
#pragma unroll
      for (int r = 0; r < 4; ++r)
        Mred[wave][mi * 16 + (lane >> 4) * 4 + r] = mx[mi][r];
  }
  __syncthreads();
  float M[4][4];
#pragma unroll
  for (int mi = 0; mi < 4; ++mi)
#pragma unroll
    for (int r = 0; r < 4; ++r) {
      const int row = mi * 16 + (lane >> 4) * 4 + r;
      float m = Mred[0][row];
#pragma unroll
      for (int w = 1; w < 8; ++w) m = fmaxf(m, Mred[w][row]);
      M[mi][r] = m;
    }
  float l[4][4];
#pragma unroll
  for (int mi = 0; mi < 4; ++mi)
#pragma unroll
    for (int r = 0; r < 4; ++r) l[mi][r] = 0.f;
#pragma unroll
  for (int nt = 0; nt < 4; ++nt)
#pragma unroll
    for (int mi = 0; mi < 4; ++mi)
#pragma unroll
      for (int ni = 0; ni < 2; ++ni)
#pragma unroll
        for (int r = 0; r < 4; ++r) {
          const float e = __expf(s4[nt][mi][ni][r] - M[mi][r]);
          s4[nt][mi][ni][r] = e;
          l[mi][r] += e;
        }
#pragma unroll
  for (int off = 1; off < 16; off <<= 1)
#pragma unroll
    for (int mi = 0; mi < 4; ++mi)
#pragma unroll
      for (int r = 0; r < 4; ++r) l[mi][r] += __shfl_xor(l[mi][r], off);
  if ((lane & 15) == 0) {
#pragma unroll
    for (int mi = 0; mi < 4; ++mi)
#pragma unroll
      for (int r = 0; r < 4; ++r)
        Lred[wave][mi * 16 + (lane >> 4) * 4 + r] = l[mi][r];
  }
  __syncthreads();
  float inv[4][4];
#pragma unroll
  for (int mi = 0; mi < 4; ++mi)
#pragma unroll
    for (int r = 0; r < 4; ++r) {
      const int row = mi * 16 + (lane >> 4) * 4 + r;
      float t = 0.f;
#pragma unroll
      for (int w = 0; w < 8; ++w) t += Lred[w][row];
      inv[mi][r] = 1.f / t;
    }

  // ---- phase 5: write P ----
#pragma unroll
  for (int nt = 0; nt < 4; ++nt)
#pragma unroll
    for (int mi = 0; mi < 4; ++mi)
#pragma unroll
      for (int ni = 0; ni < 2; ++ni) {
        const int t = nt * 256 + wave * 32 + ni * 16 + (lane & 15);
#pragma unroll
        for (int r = 0; r < 4; ++r) {
          const int p = m0 + mi * 16 + (lane >> 4) * 4 + r;
          if (p < PP)
            pbf[((size_t)(b * PP + p)) * TT + t] = f2bf(s4[nt][mi][ni][r] * inv[mi][r]);
        }
      }
}

// ================= K6: pout = P @ tok (64-tile pipelined). grid (BB, 4), 16 K-steps =================
__global__ __launch_bounds__(512) void k_pout(const u16* __restrict__ pbf,
                                              const u16* __restrict__ tokT,
                                              u16* __restrict__ out)
{
  __shared__ u16 Ab[2][64 * 64];
  __shared__ u16 Bb[2][256 * 64];
  const int tid = threadIdx.x;
  const int lane = tid & 63, wave = tid >> 6;
  f32x4 acc[4][2] = {};
  const int b = blockIdx.x, mh = blockIdx.y;

#define PO_A(BUF, K0) GLOAD_A1(BUF, ({ int p = mh * 64 + r; p = (p < PP) ? p : (PP - 1); \
                    &pbf[((size_t)(b * PP + p)) * TT + (K0) + ce]; }))
  PO_A(Ab[0], 0)
  GLOAD_B4(Bb[0], &tokT[((size_t)(b * DD + r)) * TT + 0 + ce])
  for (int it = 0; it < 16; ++it) {
    const int cur = it & 1;
    if (it < 15) {
      const int k0 = (it + 1) * 64;
      PO_A(Ab[cur ^ 1], k0)
      GLOAD_B4(Bb[cur ^ 1], &tokT[((size_t)(b * DD + r)) * TT + k0 + ce])
      PIPE_WAIT(5)
    } else { PIPE_WAIT(0) }
    PIPE_BAR()
    MFMA_STEP64(Ab[cur], Bb[cur])
    PIPE_END()
  }
#undef PO_A
#pragma unroll
  for (int mi = 0; mi < 4; ++mi) {
#pragma unroll
    for (int ni = 0; ni < 2; ++ni) {
      const int e = wave * 32 + ni * 16 + (lane & 15);
#pragma unroll
      for (int r = 0; r < 4; ++r) {
        const int p = mh * 64 + mi * 16 + (lane >> 4) * 4 + r;
        if (p < PP)
          out[((size_t)(b * PP + p)) * DD + e] = f2bf(acc[mi][ni][r]);
      }
    }
  }
}

// ================= K7: out = gate * (combined @ up_W^T + b), NT stores =================
__global__ __launch_bounds__(512) void k_up(const u16* __restrict__ poutbf,
                                            const u16* __restrict__ down,
                                            const u16* __restrict__ Wu,
                                            const float* __restrict__ bias,
                                            const float* __restrict__ gate,
                                            float* __restrict__ out)
{
  __shared__ u16 Ab[2][64 * 64];
  __shared__ u16 Bb[2][256 * 64];
  const int tid = threadIdx.x;
  const int lane = tid & 63, wave = tid >> 6;
  f32x4 acc[4][2] = {};
  const int m0 = blockIdx.x * 64;
  const int n0 = blockIdx.y * 256;

#define UP_A(BUF, K0) GLOAD_A1(BUF, ({ const int m = m0 + r; const int b = m / NN; const int rr = m - b * NN; \
                     const u16* base = (rr < PP) ? &poutbf[((size_t)(b * PP + rr)) * DD] \
                                                 : &down[((size_t)(b * NN + rr)) * DD]; \
                     base + (K0) + ce; }))
  UP_A(Ab[0], 0)
  GLOAD_B4(Bb[0], &Wu[(size_t)(n0 + r) * DD + 0 + ce])
  for (int it = 0; it < 4; ++it) {
    const int cur = it & 1;
    if (it < 3) {
      const int k0 = (it + 1) * 64;
      UP_A(Ab[cur ^ 1], k0)
      GLOAD_B4(Bb[cur ^ 1], &Wu[(size_t)(n0 + r) * DD + k0 + ce])
      PIPE_WAIT(5)
    } else { PIPE_WAIT(0) }
    PIPE_BAR()
    MFMA_STEP64(Ab[cur], Bb[cur])
    PIPE_END()
  }
#undef UP_A
  const float g = gate[0];
#pragma unroll
  for (int mi = 0; mi < 4; ++mi) {
#pragma unroll
    for (int ni = 0; ni < 2; ++ni) {
      const int col = n0 + wave * 32 + ni * 16 + (lane & 15);
      const float bv = bias[col];
#pragma unroll
      for (int r = 0; r < 4; ++r) {
        const int row = m0 + mi * 16 + (lane >> 4) * 4 + r;
        __builtin_nontemporal_store((acc[mi][ni][r] + bv) * g, &out[(size_t)row * CC + col]);
      }
    }
  }
}

extern "C" void kernel_launch(void* const* d_in, const int* in_sizes, int n_in,
                              void* d_out, int out_size, void* d_ws, size_t ws_size,
                              hipStream_t stream) {
  const float* x          = (const float*)d_in[0];
  const float* down_W     = (const float*)d_in[1];
  const float* down_b     = (const float*)d_in[2];
  const float* up_W       = (const float*)d_in[3];
  const float* up_b       = (const float*)d_in[4];
  const float* in_proj_W  = (const float*)d_in[5];
  const float* in_proj_b  = (const float*)d_in[6];
  const float* out_proj_W = (const float*)d_in[7];
  const float* out_proj_b = (const float*)d_in[8];
  const float* gate       = (const float*)d_in[9];
  float* out = (float*)d_out;

  char* wsb = (char*)d_ws;
  u16* down_bf = (u16*)(wsb + B_DOWN);
  u16* tokT    = (u16*)(wsb + B_TOKT);
  u16* qb      = (u16*)(wsb + B_QB);
  u16* kb      = (u16*)(wsb + B_KB);
  u16* vb      = (u16*)(wsb + B_VB);
  u16* sa_bf   = (u16*)(wsb + B_SA);
  u16* pbf     = (u16*)(wsb + B_PBF);
  u16* poutbf  = (u16*)(wsb + B_POUTBF);
  u16* Wd  = (u16*)(wsb + B_WD);
  u16* Wu  = (u16*)(wsb + B_WU);
  u16* Wip = (u16*)(wsb + B_WIP);
  u16* Wop = (u16*)(wsb + B_WOP);

  k_castw<<<dim3(768), 256, 0, stream>>>(down_W, up_W, in_proj_W, out_proj_W, Wd, Wu, Wip, Wop);
  k_down<<<dim3((BB * NN) / 64), 512, 0, stream>>>(x, Wd, down_b, down_bf, tokT);
  k_qkv<<<dim3(200, 3), 512, 0, stream>>>(down_bf, Wip, in_proj_b, qb, kb, vb);
  k_attn<<<dim3(BB * HH), 512, 0, stream>>>(qb, kb, vb, sa_bf);
  k_fuse<<<dim3(BB, 4), 512, 0, stream>>>(sa_bf, Wop, out_proj_b, down_bf, pbf);
  k_pout<<<dim3(BB, 4), 512, 0, stream>>>(pbf, tokT, poutbf);
  k_up<<<dim3((BB * NN) / 64, CC / 256), 512, 0, stream>>>(poutbf, down_bf, Wu, up_b, gate, out);
}